// Round 1
// baseline (228.993 us; speedup 1.0000x reference)
//
#include <hip/hip_runtime.h>

#define NN 100000
#define DD 384
#define CC 8

__device__ __forceinline__ constexpr int TIDX(int i, int j) { return i * (i + 1) / 2 + j; }

// Pack per-channel record: [0..35] lower-tri (i>=j) of Sigmaw[d] + wbar[d] wbar[d]^T,
// [36..43] wbar[d][0..7], [44] mbar[d], [45..47] pad.  48 floats per d, 16B aligned.
__global__ __launch_bounds__(64) void vbpca_prep(
    const float* __restrict__ mbar, const float* __restrict__ wbar,
    const float* __restrict__ Sigmaw, float* __restrict__ rec) {
  int d = blockIdx.x * 64 + threadIdx.x;
  if (d >= DD) return;
  float w[CC];
#pragma unroll
  for (int i = 0; i < CC; ++i) w[i] = wbar[d * CC + i];
  float* r = rec + d * 48;
#pragma unroll
  for (int i = 0; i < CC; ++i) {
#pragma unroll
    for (int j = 0; j <= i; ++j) {
      r[TIDX(i, j)] = Sigmaw[(size_t)d * 64 + i * 8 + j] + w[i] * w[j];
    }
  }
#pragma unroll
  for (int i = 0; i < CC; ++i) r[36 + i] = w[i];
  r[44] = mbar[d];
  r[45] = 0.f; r[46] = 0.f; r[47] = 0.f;
}

__global__ __launch_bounds__(64) void vbpca_main(
    const float* __restrict__ Y, const int* __restrict__ O,
    const float* __restrict__ rec, const float* __restrict__ vyp,
    float* __restrict__ out) {
  const int n = blockIdx.x * 64 + threadIdx.x;
  if (n >= NN) return;
  const float vy = *vyp;

  const float4* __restrict__ Y4 = reinterpret_cast<const float4*>(Y + (size_t)n * DD);
  const int4* __restrict__ O4 = reinterpret_cast<const int4*>(O + (size_t)n * DD);

  float a[36];
  float pr[CC];
#pragma unroll
  for (int k = 0; k < 36; ++k) a[k] = 0.f;
#pragma unroll
  for (int j = 0; j < CC; ++j) pr[j] = 0.f;

  // Main accumulation: 96 iterations of 4 channels each.
  for (int c = 0; c < DD / 4; ++c) {
    const float4 y4 = Y4[c];
    const int4 o4 = O4[c];
    const float4* __restrict__ r4 = reinterpret_cast<const float4*>(rec) + (size_t)c * 48;
#pragma unroll
    for (int u = 0; u < 4; ++u) {
      float rv[48];
#pragma unroll
      for (int q = 0; q < 12; ++q) {
        const float4 t4 = r4[u * 12 + q];
        rv[q * 4 + 0] = t4.x; rv[q * 4 + 1] = t4.y;
        rv[q * 4 + 2] = t4.z; rv[q * 4 + 3] = t4.w;
      }
      const float yv = (u == 0) ? y4.x : (u == 1) ? y4.y : (u == 2) ? y4.z : y4.w;
      const int oi = (u == 0) ? o4.x : (u == 1) ? o4.y : (u == 2) ? o4.z : o4.w;
      const float of = (float)oi;          // mask is 0/1
      const float tv = of * (yv - rv[44]); // O * (Y - mbar)
#pragma unroll
      for (int k = 0; k < 36; ++k) a[k] = fmaf(of, rv[k], a[k]);
#pragma unroll
      for (int j = 0; j < CC; ++j) pr[j] = fmaf(tv, rv[36 + j], pr[j]);
    }
  }

  // ---- Solve: M = vy*I + A (SPD, packed lower-tri in a[] + vy on diag) ----
  // Cholesky M = L L^T
  float L[36];
#pragma unroll
  for (int j = 0; j < CC; ++j) {
    float s = a[TIDX(j, j)] + vy;
#pragma unroll
    for (int k = 0; k < CC; ++k) {
      if (k < j) s -= L[TIDX(j, k)] * L[TIDX(j, k)];
    }
    const float dj = sqrtf(s);
    L[TIDX(j, j)] = dj;
    const float invdj = 1.0f / dj;
#pragma unroll
    for (int i = j + 1; i < CC; ++i) {
      float t = a[TIDX(i, j)];
#pragma unroll
      for (int k = 0; k < CC; ++k) {
        if (k < j) t -= L[TIDX(i, k)] * L[TIDX(j, k)];
      }
      L[TIDX(i, j)] = t * invdj;
    }
  }

  // Li = L^{-1} (lower triangular)
  float invd[CC];
#pragma unroll
  for (int i = 0; i < CC; ++i) invd[i] = 1.0f / L[TIDX(i, i)];
  float Li[36];
#pragma unroll
  for (int j = 0; j < CC; ++j) {
    Li[TIDX(j, j)] = invd[j];
#pragma unroll
    for (int i = j + 1; i < CC; ++i) {
      float s = 0.f;
#pragma unroll
      for (int k = 0; k < CC; ++k) {
        if (k >= j && k < i) s += L[TIDX(i, k)] * Li[TIDX(k, j)];
      }
      Li[TIDX(i, j)] = -s * invd[i];
    }
  }

  // Sigma = vy * Li^T Li (packed lower-tri, i>=j): sum_{k>=i} Li[k][i]*Li[k][j]
  float sig[36];
#pragma unroll
  for (int i = 0; i < CC; ++i) {
#pragma unroll
    for (int j = 0; j <= i; ++j) {
      float s = 0.f;
#pragma unroll
      for (int k = 0; k < CC; ++k) {
        if (k >= i) s += Li[TIDX(k, i)] * Li[TIDX(k, j)];
      }
      sig[TIDX(i, j)] = vy * s;
    }
  }

  // xbar = M^{-1} proj = Li^T (Li proj)
  float uvec[CC];
#pragma unroll
  for (int i = 0; i < CC; ++i) {
    float s = 0.f;
#pragma unroll
    for (int j = 0; j < CC; ++j) {
      if (j <= i) s += Li[TIDX(i, j)] * pr[j];
    }
    uvec[i] = s;
  }
  float xb[CC];
#pragma unroll
  for (int l = 0; l < CC; ++l) {
    float s = 0.f;
#pragma unroll
    for (int i = 0; i < CC; ++i) {
      if (i >= l) s += Li[TIDX(i, l)] * uvec[i];
    }
    xb[l] = s;
  }

  // ---- Write outputs: xbarn [N,8] then Sigma_xn [N,8,8] ----
  float4* __restrict__ xo = reinterpret_cast<float4*>(out + (size_t)n * CC);
  xo[0] = make_float4(xb[0], xb[1], xb[2], xb[3]);
  xo[1] = make_float4(xb[4], xb[5], xb[6], xb[7]);

  float4* __restrict__ so4 =
      reinterpret_cast<float4*>(out + (size_t)NN * CC + (size_t)n * 64);
#pragma unroll
  for (int i = 0; i < CC; ++i) {
    float row[CC];
#pragma unroll
    for (int j = 0; j < CC; ++j) {
      row[j] = (j <= i) ? sig[TIDX(i, j)] : sig[TIDX(j, i)];
    }
    so4[i * 2 + 0] = make_float4(row[0], row[1], row[2], row[3]);
    so4[i * 2 + 1] = make_float4(row[4], row[5], row[6], row[7]);
  }
}

extern "C" void kernel_launch(void* const* d_in, const int* in_sizes, int n_in,
                              void* d_out, int out_size, void* d_ws, size_t ws_size,
                              hipStream_t stream) {
  const float* Y = (const float*)d_in[0];
  const int* O = (const int*)d_in[1];
  const float* mbar = (const float*)d_in[2];
  const float* wbar = (const float*)d_in[3];
  const float* Sigmaw = (const float*)d_in[4];
  const float* vyp = (const float*)d_in[5];
  float* out = (float*)d_out;
  float* rec = (float*)d_ws;  // 384*48*4 = 73728 bytes

  vbpca_prep<<<(DD + 63) / 64, 64, 0, stream>>>(mbar, wbar, Sigmaw, rec);
  vbpca_main<<<(NN + 63) / 64, 64, 0, stream>>>(Y, O, rec, vyp, out);
}